// Round 2
// baseline (1184.741 us; speedup 1.0000x reference)
//
#include <hip/hip_runtime.h>
#include <cstdint>
#include <cstddef>

#define DIM 384
#define HEADS 8
#define NBATCH 8
#define NPIX 16384   // 128*128
#define CPH 48       // channels per head

typedef unsigned short h16_t;   // fp16 bits
typedef __attribute__((ext_vector_type(8))) _Float16 half8;
typedef __attribute__((ext_vector_type(4))) float floatx4;

__device__ __forceinline__ h16_t f2h(float f) {
  _Float16 h = (_Float16)f;          // v_cvt_f16_f32, RNE
  return __builtin_bit_cast(h16_t, h);
}
__device__ __forceinline__ float h2f(h16_t u) {
  return (float)__builtin_bit_cast(_Float16, u);
}

__device__ __forceinline__ void gload_lds16(const void* g, void* l) {
  __builtin_amdgcn_global_load_lds(
      (const __attribute__((address_space(1))) unsigned int*)g,
      (__attribute__((address_space(3))) unsigned int*)l, 16, 0, 0);
}

// ---------------------------------------------------------------------------
// fp32 -> fp16 elementwise convert (weights)
// ---------------------------------------------------------------------------
__global__ void convert_h16_kernel(const float* __restrict__ in, h16_t* __restrict__ out, int n) {
  int i = blockIdx.x * blockDim.x + threadIdx.x;
  if (i < n) out[i] = f2h(in[i]);
}

// ---------------------------------------------------------------------------
// Transpose [b][C][Nn] -> [b][Nn][C], output fp16. T = float or unsigned short.
// grid: (Nn/64, C/64, b), block 256
// ---------------------------------------------------------------------------
template <typename T>
__global__ __launch_bounds__(256) void transpose_conv_kernel(
    const T* __restrict__ in, h16_t* __restrict__ out, int C, int Nn) {
  __shared__ h16_t tile[64][68];
  int b = blockIdx.z;
  int c0 = blockIdx.y * 64;
  int n0 = blockIdx.x * 64;
  const T* src = in + (size_t)b * C * Nn;
  h16_t* dst = out + (size_t)b * Nn * C;
  int t = threadIdx.x;
  int cl = t >> 4;
  int n4 = (t & 15) << 2;
#pragma unroll
  for (int p = 0; p < 4; ++p) {
    int c = cl + p * 16;
    const T* sp = src + (size_t)(c0 + c) * Nn + n0 + n4;
    h16_t v0, v1, v2, v3;
    if (sizeof(T) == 4) {
      float4 f = *(const float4*)sp;
      v0 = f2h(f.x); v1 = f2h(f.y); v2 = f2h(f.z); v3 = f2h(f.w);
    } else {
      ushort4 u = *(const ushort4*)sp;
      v0 = u.x; v1 = u.y; v2 = u.z; v3 = u.w;
    }
    tile[n4 + 0][c] = v0;
    tile[n4 + 1][c] = v1;
    tile[n4 + 2][c] = v2;
    tile[n4 + 3][c] = v3;
  }
  __syncthreads();
  int nl = t >> 4;
  int c4 = (t & 15) << 2;
#pragma unroll
  for (int p = 0; p < 4; ++p) {
    int n = nl + p * 16;
    ushort4 w;
    w.x = tile[n][c4 + 0];
    w.y = tile[n][c4 + 1];
    w.z = tile[n][c4 + 2];
    w.w = tile[n][c4 + 3];
    *(ushort4*)(dst + (size_t)(n0 + n) * C + c0 + c4) = w;
  }
}

// ---------------------------------------------------------------------------
// fp16 MFMA GEMM (gemm_bt): C[b][m][n] = sum_k A[m][k] * B[b][n][k]
// A: [384][384] fp16 (ABATCH -> per-batch stride 384*384)
// B: [b][16384][384] fp16
// grid: (16384/128, 384/128, 8), block 256 (4 waves, 2x2, each 64x64)
// ---------------------------------------------------------------------------
template <bool F32OUT, bool ABATCH>
__global__ __launch_bounds__(256) void gemm_bt_kernel(
    const h16_t* __restrict__ Aall, const h16_t* __restrict__ Ball, void* __restrict__ Cout) {
  __shared__ __align__(16) h16_t lds[16384];  // lA [128 rows][64], lB behind it
  h16_t* lA = lds;
  h16_t* lB = lds + 8192;
  int b = blockIdx.z, mb = blockIdx.y, nb = blockIdx.x;
  const h16_t* A = Aall + (ABATCH ? (size_t)b * DIM * DIM : (size_t)0) + (size_t)mb * 128 * DIM;
  const h16_t* B = Ball + ((size_t)b * NPIX + (size_t)nb * 128) * DIM;
  int tid = threadIdx.x;
  int wid = tid >> 6, lane = tid & 63;
  int wi = wid >> 1, wj = wid & 1;
  int quad = lane >> 4, l15 = lane & 15;
  int srow = lane >> 3;                  // 0..7
  int schunk = (lane & 7) ^ srow;        // XOR swizzle: logical 16B-chunk this lane fetches

  floatx4 acc[4][4];
#pragma unroll
  for (int i = 0; i < 4; ++i)
#pragma unroll
    for (int j = 0; j < 4; ++j) acc[i][j] = (floatx4)0.0f;

  for (int kt = 0; kt < 6; ++kt) {  // K = 384 = 6 * 64
    __syncthreads();
#pragma unroll
    for (int t = 0; t < 4; ++t) {
      int r = (wid * 4 + t) * 8 + srow;  // tile row 0..127
      const h16_t* ga = A + (size_t)r * DIM + kt * 64 + schunk * 8;
      const h16_t* gb = B + (size_t)r * DIM + kt * 64 + schunk * 8;
      char* la = (char*)lA + (wid * 4 + t) * 1024 + lane * 16;
      char* lb = (char*)lB + (wid * 4 + t) * 1024 + lane * 16;
      gload_lds16(ga, la);
      gload_lds16(gb, lb);
    }
    __syncthreads();
#pragma unroll
    for (int ks = 0; ks < 2; ++ks) {
      half8 af[4], bfr[4];
      int ph = (((ks << 2) | quad) ^ (l15 & 7)) << 4;  // physical 16B chunk byte offset
#pragma unroll
      for (int i = 0; i < 4; ++i)
        af[i] = *(const half8*)((const char*)lA + (wi * 64 + i * 16 + l15) * 128 + ph);
#pragma unroll
      for (int j = 0; j < 4; ++j)
        bfr[j] = *(const half8*)((const char*)lB + (wj * 64 + j * 16 + l15) * 128 + ph);
#pragma unroll
      for (int i = 0; i < 4; ++i)
#pragma unroll
        for (int j = 0; j < 4; ++j)
          acc[i][j] = __builtin_amdgcn_mfma_f32_16x16x32_f16(af[i], bfr[j], acc[i][j], 0, 0, 0);
    }
  }
  // epilogue: D row = A-row (m, o-dim), col = B-row (n-dim)
  int orow0 = mb * 128 + wi * 64 + quad * 4;
  int ncol0 = nb * 128 + wj * 64 + l15;
#pragma unroll
  for (int i = 0; i < 4; ++i) {
#pragma unroll
    for (int j = 0; j < 4; ++j) {
#pragma unroll
      for (int r = 0; r < 4; ++r) {
        size_t idx = ((size_t)b * DIM + (orow0 + i * 16 + r)) * NPIX + (ncol0 + j * 16);
        if (F32OUT)
          ((float*)Cout)[idx] = acc[i][j][r];
        else
          ((h16_t*)Cout)[idx] = f2h(acc[i][j][r]);
      }
    }
  }
}

// ---------------------------------------------------------------------------
// Depthwise 3x3, SAME padding, fp16 in/out, fp32 weights & arithmetic.
// Optionally accumulates sum of squares (of the fp16-rounded outputs) per plane.
// grid: (C=384, b=8), block 256. Each block = one (b,c) 128x128 plane.
// ---------------------------------------------------------------------------
__device__ __forceinline__ void load_row6(const h16_t* ip, int yy, int x0, float* r) {
  if ((unsigned)yy > 127u) {
    r[0] = r[1] = r[2] = r[3] = r[4] = r[5] = 0.f;
    return;
  }
  const h16_t* row = ip + (yy << 7) + x0;
  ushort4 m = *(const ushort4*)row;
  r[0] = (x0 > 0) ? h2f(row[-1]) : 0.f;
  r[1] = h2f(m.x); r[2] = h2f(m.y); r[3] = h2f(m.z); r[4] = h2f(m.w);
  r[5] = (x0 < 124) ? h2f(row[4]) : 0.f;
}

__global__ __launch_bounds__(256) void dwconv_kernel(
    const h16_t* __restrict__ in, const float* __restrict__ wbase,
    h16_t* __restrict__ out, float* __restrict__ norm2) {
  int c = blockIdx.x, b = blockIdx.y;
  const h16_t* ip = in + ((size_t)(b * DIM + c) << 14);
  h16_t* op = out + ((size_t)(b * DIM + c) << 14);
  const float* wp = wbase + c * 9;
  float w0 = wp[0], w1 = wp[1], w2 = wp[2], w3 = wp[3], w4 = wp[4];
  float w5 = wp[5], w6 = wp[6], w7 = wp[7], w8 = wp[8];
  float ssum = 0.f;
  for (int t = threadIdx.x; t < 4096; t += 256) {
    int y = t >> 5;
    int x0 = (t & 31) << 2;
    float r0[6], r1[6], r2[6];
    load_row6(ip, y - 1, x0, r0);
    load_row6(ip, y,     x0, r1);
    load_row6(ip, y + 1, x0, r2);
    ushort4 st;
#pragma unroll
    for (int i = 0; i < 4; ++i) {
      float o = w0 * r0[i] + w1 * r0[i + 1] + w2 * r0[i + 2]
              + w3 * r1[i] + w4 * r1[i + 1] + w5 * r1[i + 2]
              + w6 * r2[i] + w7 * r2[i + 1] + w8 * r2[i + 2];
      h16_t ob = f2h(o);
      float of = h2f(ob);
      ssum += of * of;
      if (i == 0) st.x = ob; else if (i == 1) st.y = ob; else if (i == 2) st.z = ob; else st.w = ob;
    }
    *(ushort4*)(op + (y << 7) + x0) = st;
  }
  if (norm2 != nullptr) {
    __shared__ float red[256];
    int tid = threadIdx.x;
    red[tid] = ssum;
    __syncthreads();
    for (int s = 128; s > 0; s >>= 1) {
      if (tid < s) red[tid] += red[tid + s];
      __syncthreads();
    }
    if (tid == 0) norm2[b * DIM + c] = red[0];
  }
}

// ---------------------------------------------------------------------------
// attn Gram: attn[bh][c][d] += sum_n q[b][h*48+c][n] * k[b][h*48+d][n]
// q,k fp16 [b][384][16384] (n-contiguous = K-contiguous: register-direct MFMA)
// grid: (8 K-chunks, 64 bh), block 64 (1 wave, 3x3 16-tiles). fp32 atomics.
// ---------------------------------------------------------------------------
__global__ __launch_bounds__(64) void attn_gemm_kernel(
    const h16_t* __restrict__ q, const h16_t* __restrict__ k, float* __restrict__ attn) {
  int chunk = blockIdx.x, bh = blockIdx.y;
  int b = bh >> 3, h = bh & 7;
  const h16_t* qb = q + ((size_t)(b * DIM + h * CPH) << 14);
  const h16_t* kb = k + ((size_t)(b * DIM + h * CPH) << 14);
  int lane = threadIdx.x;
  int quad = lane >> 4, l15 = lane & 15;
  int off0 = chunk * 2048 + quad * 8;
  floatx4 acc[3][3];
#pragma unroll
  for (int i = 0; i < 3; ++i)
#pragma unroll
    for (int j = 0; j < 3; ++j) acc[i][j] = (floatx4)0.0f;
  for (int s = 0; s < 64; ++s) {
    int off = off0 + s * 32;
    half8 af[3], bfr[3];
#pragma unroll
    for (int i = 0; i < 3; ++i) {
      af[i]  = *(const half8*)(qb + ((size_t)(i * 16 + l15) << 14) + off);
      bfr[i] = *(const half8*)(kb + ((size_t)(i * 16 + l15) << 14) + off);
    }
#pragma unroll
    for (int i = 0; i < 3; ++i)
#pragma unroll
      for (int j = 0; j < 3; ++j)
        acc[i][j] = __builtin_amdgcn_mfma_f32_16x16x32_f16(af[i], bfr[j], acc[i][j], 0, 0, 0);
  }
  float* ap = attn + (size_t)bh * CPH * CPH;
#pragma unroll
  for (int i = 0; i < 3; ++i)
#pragma unroll
    for (int j = 0; j < 3; ++j)
#pragma unroll
      for (int r = 0; r < 4; ++r)
        atomicAdd(&ap[(i * 16 + quad * 4 + r) * CPH + j * 16 + l15], acc[i][j][r]);
}

// ---------------------------------------------------------------------------
// Per-(b,h): scale attn by 1/(|q||k|)*temp, 4x top-m softmax combined with a_mix,
// then fold with proj_w: Bmat[b][o][h*48+d] = sum_c proj_w[o][h*48+c]*Acomb[c][d]
// grid: 64 blocks, 256 threads
// ---------------------------------------------------------------------------
__global__ __launch_bounds__(256) void combine_kernel(
    const float* __restrict__ attn, const float* __restrict__ n2q, const float* __restrict__ n2k,
    const float* __restrict__ temp, const float* __restrict__ amix,
    const float* __restrict__ projw, h16_t* __restrict__ Bmat) {
  int bh = blockIdx.x;
  int b = bh >> 3, h = bh & 7;
  __shared__ float Asc[CPH][CPH];
  __shared__ float Ex[CPH][CPH];
  __shared__ float thr[CPH][4];
  __shared__ float rmax[CPH];
  __shared__ float den[CPH][4];
  __shared__ float rsq[CPH], rsk[CPH];
  int tid = threadIdx.x;
  if (tid < CPH) {
    float nq = sqrtf(n2q[b * DIM + h * CPH + tid]);
    rsq[tid] = 1.f / fmaxf(nq, 1e-12f);
    float nk = sqrtf(n2k[b * DIM + h * CPH + tid]);
    rsk[tid] = 1.f / fmaxf(nk, 1e-12f);
  }
  __syncthreads();
  float tscale = temp[h];
  const float* ap = attn + (size_t)bh * CPH * CPH;
  for (int idx = tid; idx < CPH * CPH; idx += 256) {
    int c = idx / CPH, d = idx - c * CPH;
    Asc[c][d] = ap[idx] * rsq[c] * rsk[d] * tscale;
  }
  __syncthreads();
  const int M0 = 24, M1 = 32, M2 = 36, M3 = 38;  // C//2, 2C//3, 3C//4, 4C//5
  for (int idx = tid; idx < CPH * CPH; idx += 256) {
    int c = idx / CPH, d = idx - c * CPH;
    float a = Asc[c][d];
    int gt = 0, ge = 0;
    float mx = -1e30f;
    for (int e = 0; e < CPH; ++e) {
      float v = Asc[c][e];
      gt += (v > a);
      ge += (v >= a);
      mx = fmaxf(mx, v);
    }
    if (d == 0) rmax[c] = mx;
    // a is the m-th largest iff (#>a) < m <= (#>=a); ties write identical bits
    if (gt < M0 && ge >= M0) thr[c][0] = a;
    if (gt < M1 && ge >= M1) thr[c][1] = a;
    if (gt < M2 && ge >= M2) thr[c][2] = a;
    if (gt < M3 && ge >= M3) thr[c][3] = a;
  }
  __syncthreads();
  for (int idx = tid; idx < CPH * CPH; idx += 256) {
    int c = idx / CPH, d = idx - c * CPH;
    Ex[c][d] = expf(Asc[c][d] - rmax[c]);
  }
  __syncthreads();
  if (tid < CPH * 4) {
    int c = tid >> 2, mi = tid & 3;
    float t_ = thr[c][mi];
    float s = 0.f;
    for (int e = 0; e < CPH; ++e)
      if (Asc[c][e] >= t_) s += Ex[c][e];
    den[c][mi] = s;
  }
  __syncthreads();
  float a0 = amix[0], a1 = amix[1], a2 = amix[2], a3 = amix[3];
  for (int idx = tid; idx < CPH * CPH; idx += 256) {
    int c = idx / CPH, d = idx - c * CPH;
    float a = Asc[c][d];
    float s = 0.f;
    if (a >= thr[c][0]) s += a0 / den[c][0];
    if (a >= thr[c][1]) s += a1 / den[c][1];
    if (a >= thr[c][2]) s += a2 / den[c][2];
    if (a >= thr[c][3]) s += a3 / den[c][3];
    Ex[c][d] = Ex[c][d] * s;  // Acomb
  }
  __syncthreads();
  for (int idx = tid; idx < DIM * CPH; idx += 256) {
    int o = idx / CPH, d = idx - (idx / CPH) * CPH;
    const float* pw = projw + (size_t)o * DIM + h * CPH;
    float s = 0.f;
    for (int c2 = 0; c2 < CPH; ++c2) s += pw[c2] * Ex[c2][d];
    Bmat[((size_t)b * DIM + o) * DIM + h * CPH + d] = f2h(s);
  }
}

// ---------------------------------------------------------------------------
extern "C" void kernel_launch(void* const* d_in, const int* in_sizes, int n_in,
                              void* d_out, int out_size, void* d_ws, size_t ws_size,
                              hipStream_t stream) {
  const float* x_q    = (const float*)d_in[0];
  const float* x_kv   = (const float*)d_in[1];
  const float* q_w    = (const float*)d_in[2];
  const float* q_dw   = (const float*)d_in[3];
  const float* kv_w   = (const float*)d_in[4];
  const float* kv_dw  = (const float*)d_in[5];
  const float* proj_w = (const float*)d_in[6];
  const float* temp   = (const float*)d_in[7];
  const float* amix   = (const float*)d_in[8];

  char* ws = (char*)d_ws;
  const size_t SLOT = (size_t)NBATCH * NPIX * DIM * 2;  // 100,663,296 B
  h16_t* S0 = (h16_t*)(ws);             // xqT -> xkvT
  h16_t* S1 = (h16_t*)(ws + SLOT);      // Yq -> Yk -> Yv
  h16_t* S2 = (h16_t*)(ws + 2 * SLOT);  // q  -> v
  h16_t* S3 = (h16_t*)(ws + 3 * SLOT);  // k  -> vT
  char* p = ws + 4 * SLOT;
  h16_t* WqB  = (h16_t*)p; p += (size_t)DIM * DIM * 2;
  h16_t* WkvB = (h16_t*)p; p += (size_t)2 * DIM * DIM * 2;
  float* n2q  = (float*)p;  p += (size_t)NBATCH * DIM * 4;
  float* n2k  = (float*)p;  p += (size_t)NBATCH * DIM * 4;
  float* attn = (float*)p;  p += (size_t)64 * CPH * CPH * 4;
  h16_t* Bmat = (h16_t*)p; p += (size_t)NBATCH * DIM * DIM * 2;

  hipMemsetAsync(attn, 0, (size_t)64 * CPH * CPH * 4, stream);

  convert_h16_kernel<<<dim3((DIM * DIM + 255) / 256), 256, 0, stream>>>(q_w, WqB, DIM * DIM);
  convert_h16_kernel<<<dim3((2 * DIM * DIM + 255) / 256), 256, 0, stream>>>(kv_w, WkvB, 2 * DIM * DIM);

  dim3 tgrid(NPIX / 64, DIM / 64, NBATCH);
  dim3 ggrid(NPIX / 128, DIM / 128, NBATCH);

  // q path
  transpose_conv_kernel<float><<<tgrid, 256, 0, stream>>>(x_q, S0, DIM, NPIX);
  gemm_bt_kernel<false, false><<<ggrid, 256, 0, stream>>>(WqB, S0, S1);
  dwconv_kernel<<<dim3(DIM, NBATCH), 256, 0, stream>>>(S1, q_dw, S2, n2q);

  // k path
  transpose_conv_kernel<float><<<tgrid, 256, 0, stream>>>(x_kv, S0, DIM, NPIX);
  gemm_bt_kernel<false, false><<<ggrid, 256, 0, stream>>>(WkvB, S0, S1);
  dwconv_kernel<<<dim3(DIM, NBATCH), 256, 0, stream>>>(S1, kv_dw, S3, n2k);

  // attention (48x48 per b,h) + top-m combine + proj fold
  attn_gemm_kernel<<<dim3(8, 64), 64, 0, stream>>>(S2, S3, attn);
  combine_kernel<<<dim3(64), 256, 0, stream>>>(attn, n2q, n2k, temp, amix, proj_w, Bmat);

  // v path (reuses xkvT in S0; q/k slots now dead)
  gemm_bt_kernel<false, false><<<ggrid, 256, 0, stream>>>(WkvB + (size_t)DIM * DIM, S0, S1);
  dwconv_kernel<<<dim3(DIM, NBATCH), 256, 0, stream>>>(S1, kv_dw + (size_t)DIM * 9, S2, nullptr);
  transpose_conv_kernel<unsigned short><<<tgrid, 256, 0, stream>>>(S2, S3, DIM, NPIX);

  // fused (proj ∘ attn-mix) @ v  -> d_out fp32
  gemm_bt_kernel<true, true><<<ggrid, 256, 0, stream>>>(Bmat, S3, d_out);
}